// Round 2
// baseline (288.450 us; speedup 1.0000x reference)
//
#include <hip/hip_runtime.h>

// GCLSTM with H=C=None collapses to: gates from x@Wx only (conv term = bconv
// constant), forget gate dead (C_prev=0), graph entirely unused.
//   h1 = sig(zo)*tanh(sig(zi)*tanh(zc)),  z* = x@Wx1[:,gate]+bx1+bconv1
//   h2 = same with Wx2/bx2/bconv2; out = relu(h2)@Wl + bl
//
// R2 changes vs R1 (171 us main kernel, VALUBusy 23%, VGPR 72):
//  - __launch_bounds__(64, 1): R1's default cap made the allocator drop the
//    x row out of registers (VGPR=72 < the 128 needed) and re-load x from
//    global every j-iteration -> latency-bound. Allow full 512-VGPR budget.
//  - j-loop in pairs: 6 independent FMA chains, lets compiler pipeline the
//    wave-uniform weight s_loads across iterations.
//  - pack kernel: coalesced reads (linear over input), scattered writes.

#define NODES 100000

typedef float v2f __attribute__((ext_vector_type(2)));

__device__ __forceinline__ float fast_sigmoid(float z) {
  float t = __builtin_amdgcn_exp2f(z * -1.44269504088896f);
  return __builtin_amdgcn_rcpf(1.0f + t);
}
__device__ __forceinline__ float fast_tanh(float z) {
  float t = __builtin_amdgcn_exp2f(z * 2.88539008177793f);
  return 1.0f - 2.0f * __builtin_amdgcn_rcpf(t + 1.0f);
}

// ws float layout:
//   [0      : 19200) WT1 [3][50][128]  (gates i,c,o; k contiguous)
//   [19200  : 19350) B1  [3][50]       bx1+bconv1 fused
//   [19350  : 22350) WT2 [3][20][50]
//   [22350  : 22410) B2  [3][20]
__global__ void pack_weights(const float* __restrict__ Wx1,
                             const float* __restrict__ bx1,
                             const float* __restrict__ bconv1,
                             const float* __restrict__ Wx2,
                             const float* __restrict__ bx2,
                             const float* __restrict__ bconv2,
                             float* __restrict__ ws) {
  const int stride = gridDim.x * blockDim.x;
  const int tid = blockIdx.x * blockDim.x + threadIdx.x;

  // Wx1 is [128][200]; coalesced read, scatter write of live gate cols.
  for (int idx = tid; idx < 128 * 200; idx += stride) {
    int k = idx / 200;
    int c = idx % 200;
    int g = c / 50;          // 0=i 1=f 2=c 3=o
    int j = c % 50;
    int gm = (g == 0) ? 0 : (g == 2) ? 1 : (g == 3) ? 2 : -1;
    if (gm >= 0) ws[gm * 6400 + j * 128 + k] = Wx1[idx];
  }
  for (int idx = tid; idx < 150; idx += stride) {
    int j = idx % 50;
    int g = idx / 50;
    int gs = (g == 0) ? 0 : (g == 1) ? 2 : 3;
    ws[19200 + idx] = bx1[gs * 50 + j] + bconv1[gs * 50 + j];
  }
  // Wx2 is [50][80]
  for (int idx = tid; idx < 50 * 80; idx += stride) {
    int k = idx / 80;
    int c = idx % 80;
    int g = c / 20;
    int j = c % 20;
    int gm = (g == 0) ? 0 : (g == 2) ? 1 : (g == 3) ? 2 : -1;
    if (gm >= 0) ws[19350 + gm * 1000 + j * 50 + k] = Wx2[idx];
  }
  for (int idx = tid; idx < 60; idx += stride) {
    int j = idx % 20;
    int g = idx / 20;
    int gs = (g == 0) ? 0 : (g == 1) ? 2 : 3;
    ws[22350 + idx] = bx2[gs * 20 + j] + bconv2[gs * 20 + j];
  }
}

__global__ __launch_bounds__(64, 1) void gclstm_main(
    const float* __restrict__ x, const float* __restrict__ wsf,
    const float* __restrict__ Wl, const float* __restrict__ blp,
    float* __restrict__ out) {
  const float* WT1 = wsf;
  const float* B1  = wsf + 19200;
  const float* WT2 = wsf + 19350;
  const float* B2  = wsf + 22350;

  __shared__ float h1s[64 * 51];

  const int tid = threadIdx.x;
  const int n = blockIdx.x * 64 + tid;
  const bool valid = (n < NODES);
  const int nn = valid ? n : (NODES - 1);

  // x row -> 64 float2 regs (128 VGPRs; launch_bounds(64,1) allows it)
  v2f xv[64];
  {
    const float4* xr = (const float4*)(x + (size_t)nn * 128);
#pragma unroll
    for (int i = 0; i < 32; ++i) {
      float4 t = xr[i];
      v2f a; a.x = t.x; a.y = t.y;
      v2f b; b.x = t.z; b.y = t.w;
      xv[2 * i] = a;
      xv[2 * i + 1] = b;
    }
  }

  // ---- layer 1: 50 channels x 3 live gates, K=128, j in pairs ----
  for (int j = 0; j < 50; j += 2) {
    const v2f* wi0 = (const v2f*)(WT1 + (size_t)j * 128);
    const v2f* wc0 = (const v2f*)(WT1 + (size_t)(50 + j) * 128);
    const v2f* wo0 = (const v2f*)(WT1 + (size_t)(100 + j) * 128);
    const v2f* wi1 = (const v2f*)(WT1 + (size_t)(j + 1) * 128);
    const v2f* wc1 = (const v2f*)(WT1 + (size_t)(51 + j) * 128);
    const v2f* wo1 = (const v2f*)(WT1 + (size_t)(101 + j) * 128);
    v2f ai0 = {B1[j], 0.f},      ai1 = {B1[j + 1], 0.f};
    v2f ac0 = {B1[50 + j], 0.f}, ac1 = {B1[51 + j], 0.f};
    v2f ao0 = {B1[100 + j], 0.f}, ao1 = {B1[101 + j], 0.f};
#pragma unroll
    for (int k = 0; k < 64; ++k) {
      v2f xk = xv[k];
      ai0 += xk * wi0[k];
      ac0 += xk * wc0[k];
      ao0 += xk * wo0[k];
      ai1 += xk * wi1[k];
      ac1 += xk * wc1[k];
      ao1 += xk * wo1[k];
    }
    {
      float I = fast_sigmoid(ai0.x + ai0.y);
      float T = fast_tanh(ac0.x + ac0.y);
      float O = fast_sigmoid(ao0.x + ao0.y);
      h1s[tid * 51 + j] = O * fast_tanh(I * T);
    }
    {
      float I = fast_sigmoid(ai1.x + ai1.y);
      float T = fast_tanh(ac1.x + ac1.y);
      float O = fast_sigmoid(ao1.x + ao1.y);
      h1s[tid * 51 + j + 1] = O * fast_tanh(I * T);
    }
  }

  // h1 back to regs (own lane's data; no barrier needed)
  v2f hv[25];
#pragma unroll
  for (int k = 0; k < 25; ++k) {
    v2f a;
    a.x = h1s[tid * 51 + 2 * k];
    a.y = h1s[tid * 51 + 2 * k + 1];
    hv[k] = a;
  }

  // ---- layer 2 (K=50) fused with relu + head ----
  float o = 0.f;
  for (int j = 0; j < 20; j += 2) {
    const v2f* wi0 = (const v2f*)(WT2 + (size_t)j * 50);
    const v2f* wc0 = (const v2f*)(WT2 + (size_t)(20 + j) * 50);
    const v2f* wo0 = (const v2f*)(WT2 + (size_t)(40 + j) * 50);
    const v2f* wi1 = (const v2f*)(WT2 + (size_t)(j + 1) * 50);
    const v2f* wc1 = (const v2f*)(WT2 + (size_t)(21 + j) * 50);
    const v2f* wo1 = (const v2f*)(WT2 + (size_t)(41 + j) * 50);
    v2f ai0 = {B2[j], 0.f},      ai1 = {B2[j + 1], 0.f};
    v2f ac0 = {B2[20 + j], 0.f}, ac1 = {B2[21 + j], 0.f};
    v2f ao0 = {B2[40 + j], 0.f}, ao1 = {B2[41 + j], 0.f};
#pragma unroll
    for (int k = 0; k < 25; ++k) {
      v2f hk = hv[k];
      ai0 += hk * wi0[k];
      ac0 += hk * wc0[k];
      ao0 += hk * wo0[k];
      ai1 += hk * wi1[k];
      ac1 += hk * wc1[k];
      ao1 += hk * wo1[k];
    }
    {
      float I = fast_sigmoid(ai0.x + ai0.y);
      float T = fast_tanh(ac0.x + ac0.y);
      float O = fast_sigmoid(ao0.x + ao0.y);
      float h2 = O * fast_tanh(I * T);
      o = fmaf(fmaxf(h2, 0.f), Wl[j], o);
    }
    {
      float I = fast_sigmoid(ai1.x + ai1.y);
      float T = fast_tanh(ac1.x + ac1.y);
      float O = fast_sigmoid(ao1.x + ao1.y);
      float h2 = O * fast_tanh(I * T);
      o = fmaf(fmaxf(h2, 0.f), Wl[j + 1], o);
    }
  }

  if (valid) out[n] = o + blp[0];
}

extern "C" void kernel_launch(void* const* d_in, const int* in_sizes, int n_in,
                              void* d_out, int out_size, void* d_ws, size_t ws_size,
                              hipStream_t stream) {
  (void)in_sizes; (void)n_in; (void)out_size; (void)ws_size;
  const float* x      = (const float*)d_in[0];
  // d_in[1] edge_index, d_in[2] edge_weight, d_in[5] theta1, d_in[9] theta2: dead
  const float* Wx1    = (const float*)d_in[3];
  const float* bx1    = (const float*)d_in[4];
  const float* bconv1 = (const float*)d_in[6];
  const float* Wx2    = (const float*)d_in[7];
  const float* bx2    = (const float*)d_in[8];
  const float* bconv2 = (const float*)d_in[10];
  const float* Wl     = (const float*)d_in[11];
  const float* bl     = (const float*)d_in[12];
  float* ws = (float*)d_ws;  // needs 22410 floats (~90 KB)

  hipLaunchKernelGGL(pack_weights, dim3(128), dim3(256), 0, stream,
                     Wx1, bx1, bconv1, Wx2, bx2, bconv2, ws);
  hipLaunchKernelGGL(gclstm_main, dim3((NODES + 63) / 64), dim3(64), 0, stream,
                     x, ws, Wl, bl, (float*)d_out);
}

// Round 3
// 138.646 us; speedup vs baseline: 2.0805x; 2.0805x over previous
//
#include <hip/hip_runtime.h>

// GCLSTM with H=C=None collapses to: gates from x@Wx only (conv = bconv const),
// forget gate dead, graph unused.
//   h1 = sig(zo)*tanh(sig(zi)*tanh(zc)),  z = x@Wx1[:,{i,c,o}] + bx1 + bconv1
//   h2 = same with Wx2; out = relu(h2)@Wl + bl
//
// R3: MFMA rewrite. R2 showed thread-per-node is grid-capped at 19% occupancy
// and latency-bound (VALUBusy 18%). Here: one wave per 16-node tile,
// 16x16x32 bf16 MFMA, B pre-packed into fragment order and held in VGPRs,
// A (x) split hi/lo bf16 for accuracy, LDS round-trip for C-layout -> gates
// -> A-layout (flash-attention style, per-wave private, no barriers in loop).

#define NODES 100000
#define NTILES 6250  // NODES/16 exactly

typedef float v4f   __attribute__((ext_vector_type(4)));
typedef float fragC __attribute__((ext_vector_type(4)));
typedef short frag8 __attribute__((ext_vector_type(8)));

// ws byte offsets
#define OFF_B1H 0       // 40 frags * 1024 B = 40960
#define OFF_B2H 40960   // 8 frags * 1024 B = 8192
#define OFF_B2L 49152   // 8192
#define OFF_BIAS1 57344 // 160 f32
#define OFF_BIAS2 57984 // 64 f32
#define OFF_WL 58240    // 20 f32
#define OFF_BL 58320    // 1 f32

__device__ __forceinline__ unsigned short f2bf(float f) {
  unsigned int u = __float_as_uint(f);
  u += 0x7fffu + ((u >> 16) & 1u);  // RNE
  return (unsigned short)(u >> 16);
}
__device__ __forceinline__ float bf2f(unsigned short h) {
  return __uint_as_float(((unsigned int)h) << 16);
}
__device__ __forceinline__ float fsig(float z) {
  float t = __builtin_amdgcn_exp2f(z * -1.44269504088896f);
  return __builtin_amdgcn_rcpf(1.0f + t);
}
__device__ __forceinline__ float ftanh(float z) {
  float t = __builtin_amdgcn_exp2f(z * 2.88539008177793f);
  return 1.0f - 2.0f * __builtin_amdgcn_rcpf(t + 1.0f);
}

__device__ __forceinline__ void cvt8(const float* v, frag8& hi, frag8& lo) {
#pragma unroll
  for (int j = 0; j < 8; ++j) {
    unsigned short hs = f2bf(v[j]);
    float fh = bf2f(hs);
    hi[j] = (short)hs;
    lo[j] = (short)f2bf(v[j] - fh);
  }
}

// Pack B matrices into MFMA B-fragment order: frag (s,t), lane holds
// B[k = 32s + (lane>>4)*8 + j][n = 16t + (lane&15)] for j=0..7, bf16,
// flat ushort idx = ((s*NT + t)*64 + lane)*8 + j.
__global__ void pack_weights(const float* __restrict__ Wx1, const float* __restrict__ bx1,
                             const float* __restrict__ bconv1,
                             const float* __restrict__ Wx2, const float* __restrict__ bx2,
                             const float* __restrict__ bconv2,
                             const float* __restrict__ Wl, const float* __restrict__ bl,
                             unsigned char* __restrict__ ws) {
  const int tid = blockIdx.x * blockDim.x + threadIdx.x;
  const int stride = gridDim.x * blockDim.x;
  unsigned short* B1H = (unsigned short*)(ws + OFF_B1H);
  unsigned short* B2H = (unsigned short*)(ws + OFF_B2H);
  unsigned short* B2L = (unsigned short*)(ws + OFF_B2L);
  float* BIAS1 = (float*)(ws + OFF_BIAS1);
  float* BIAS2 = (float*)(ws + OFF_BIAS2);
  float* WLp = (float*)(ws + OFF_WL);
  float* BLp = (float*)(ws + OFF_BL);

  // B1: [128 x 160], n<150 -> gate g=n/50 (i,c,o -> cols 0,2,3 of Wx1), ch=n%50
  for (int idx = tid; idx < 20480; idx += stride) {
    int j = idx & 7, lane = (idx >> 3) & 63, ft = idx >> 9;  // ft = s*10+t
    int s = ft / 10, t = ft % 10;
    int k = 32 * s + ((lane >> 4) << 3) + j;
    int n = 16 * t + (lane & 15);
    float val = 0.f;
    if (n < 150) {
      int g = n / 50, ch = n % 50;
      int gs = (g == 0) ? 0 : (g == 1) ? 2 : 3;
      val = Wx1[k * 200 + gs * 50 + ch];
    }
    B1H[idx] = f2bf(val);
  }
  // B2: [64 x 64] zero-padded from [50 x 60]
  for (int idx = tid; idx < 4096; idx += stride) {
    int j = idx & 7, lane = (idx >> 3) & 63, ft = idx >> 9;  // ft = s*4+t
    int s = ft >> 2, t = ft & 3;
    int k = 32 * s + ((lane >> 4) << 3) + j;
    int n = 16 * t + (lane & 15);
    float val = 0.f;
    if (k < 50 && n < 60) {
      int g = n / 20, ch = n % 20;
      int gs = (g == 0) ? 0 : (g == 1) ? 2 : 3;
      val = Wx2[k * 80 + gs * 20 + ch];
    }
    unsigned short h = f2bf(val);
    B2H[idx] = h;
    B2L[idx] = f2bf(val - bf2f(h));
  }
  for (int idx = tid; idx < 160; idx += stride) {
    float v = 0.f;
    if (idx < 150) {
      int g = idx / 50, ch = idx % 50;
      int gs = (g == 0) ? 0 : (g == 1) ? 2 : 3;
      v = bx1[gs * 50 + ch] + bconv1[gs * 50 + ch];
    }
    BIAS1[idx] = v;
  }
  for (int idx = tid; idx < 64; idx += stride) {
    float v = 0.f;
    if (idx < 60) {
      int g = idx / 20, ch = idx % 20;
      int gs = (g == 0) ? 0 : (g == 1) ? 2 : 3;
      v = bx2[gs * 20 + ch] + bconv2[gs * 20 + ch];
    }
    BIAS2[idx] = v;
  }
  for (int idx = tid; idx < 20; idx += stride) WLp[idx] = Wl[idx];
  if (tid == 0) BLp[0] = bl[0];
}

__global__ __launch_bounds__(256, 1) void gclstm_main(
    const float* __restrict__ x, const unsigned char* __restrict__ wsb,
    float* __restrict__ out) {
  __shared__ float sZ[4][16 * 161];  // per-wave z scratch, pitch 161 (conflict-break)
  __shared__ float sH[4][16 * 76];   // per-wave h1 scratch, pitch 76 (16B-aligned rows)
  __shared__ float sBias1[160];
  __shared__ float sBias2[64];
  __shared__ float sWl[20];

  const int tid = threadIdx.x;
  const int lane = tid & 63;
  const int wave = tid >> 6;
  const int m = lane & 15;   // A-operand m / tile-local node for LDS reads
  const int q = lane >> 4;   // quad index

  // stage biases; zero h1 scratch (incl. K-pad cols 50..63)
  if (tid < 160) sBias1[tid] = ((const float*)(wsb + OFF_BIAS1))[tid];
  if (tid < 64) sBias2[tid] = ((const float*)(wsb + OFF_BIAS2))[tid];
  if (tid < 20) sWl[tid] = ((const float*)(wsb + OFF_WL))[tid];
  for (int i = tid; i < 4 * 16 * 76; i += 256) ((float*)sH)[i] = 0.f;
  const float blv = *(const float*)(wsb + OFF_BL);
  __syncthreads();

  // resident B fragments (VGPRs): 40 + 8 + 8 frags
  frag8 b1h[40], b2h[8], b2l[8];
  {
    const frag8* g1 = (const frag8*)(wsb + OFF_B1H);
#pragma unroll
    for (int i = 0; i < 40; ++i) b1h[i] = g1[i * 64 + lane];
    const frag8* g2h = (const frag8*)(wsb + OFF_B2H);
    const frag8* g2l = (const frag8*)(wsb + OFF_B2L);
#pragma unroll
    for (int i = 0; i < 8; ++i) {
      b2h[i] = g2h[i * 64 + lane];
      b2l[i] = g2l[i * 64 + lane];
    }
  }

  float* sZw = (float*)sZ + wave * (16 * 161);
  float* sHw = (float*)sH + wave * (16 * 76);
  const int gw = blockIdx.x * 4 + wave;  // 0..1023 global wave id

  // prefetch first tile's A (x rows, fp32): lane m -> row, quad -> k-octet
  v4f abuf[8];
  int tau = gw;
  {
    const float* xr = x + (size_t)(tau * 16 + m) * 128 + q * 8;
#pragma unroll
    for (int s = 0; s < 4; ++s) {
      abuf[2 * s] = *(const v4f*)(xr + 32 * s);
      abuf[2 * s + 1] = *(const v4f*)(xr + 32 * s + 4);
    }
  }

  for (; tau < NTILES; tau += 1024) {
    // convert A to bf16 hi/lo fragments
    frag8 ah[4], al[4];
#pragma unroll
    for (int s = 0; s < 4; ++s) {
      float av[8];
      *(v4f*)(av) = abuf[2 * s];
      *(v4f*)(av + 4) = abuf[2 * s + 1];
      cvt8(av, ah[s], al[s]);
    }
    // prefetch next tile while computing this one
    int tn = tau + 1024;
    if (tn < NTILES) {
      const float* xr = x + (size_t)(tn * 16 + m) * 128 + q * 8;
#pragma unroll
      for (int s = 0; s < 4; ++s) {
        abuf[2 * s] = *(const v4f*)(xr + 32 * s);
        abuf[2 * s + 1] = *(const v4f*)(xr + 32 * s + 4);
      }
    }

    // ---- GEMM1: z1[16 x 160] = A(hi+lo) @ B1h ----
    fragC acc[10];
#pragma unroll
    for (int t = 0; t < 10; ++t) acc[t] = (fragC){0.f, 0.f, 0.f, 0.f};
#pragma unroll
    for (int s = 0; s < 4; ++s) {
#pragma unroll
      for (int t = 0; t < 10; ++t) {
        acc[t] = __builtin_amdgcn_mfma_f32_16x16x32_bf16(ah[s], b1h[s * 10 + t], acc[t], 0, 0, 0);
        acc[t] = __builtin_amdgcn_mfma_f32_16x16x32_bf16(al[s], b1h[s * 10 + t], acc[t], 0, 0, 0);
      }
    }
    // C-layout: col = 16t + (lane&15), row = q*4 + r  ->  sZw[row][col]
#pragma unroll
    for (int t = 0; t < 10; ++t)
#pragma unroll
      for (int r = 0; r < 4; ++r)
        sZw[(q * 4 + r) * 161 + t * 16 + m] = acc[t][r];

    // gates: lane handles node=m, channels jj = q, q+4, ...
#pragma unroll
    for (int it = 0; it < 13; ++it) {
      int jj = q + 4 * it;
      if (jj < 50) {
        float zi = sZw[m * 161 + jj] + sBias1[jj];
        float zc = sZw[m * 161 + 50 + jj] + sBias1[50 + jj];
        float zo = sZw[m * 161 + 100 + jj] + sBias1[100 + jj];
        float I = fsig(zi), T = ftanh(zc), O = fsig(zo);
        sHw[m * 76 + jj] = O * ftanh(I * T);
      }
    }

    // ---- GEMM2: z2[16 x 64] = h1(hi+lo) @ B2(hi+lo), K padded to 64 ----
    frag8 hh[2], hl[2];
#pragma unroll
    for (int s = 0; s < 2; ++s) {
      float hv[8];
      *(v4f*)(hv) = *(const v4f*)(sHw + m * 76 + 32 * s + q * 8);
      *(v4f*)(hv + 4) = *(const v4f*)(sHw + m * 76 + 32 * s + q * 8 + 4);
      cvt8(hv, hh[s], hl[s]);
    }
    fragC acc2[4];
#pragma unroll
    for (int t = 0; t < 4; ++t) acc2[t] = (fragC){0.f, 0.f, 0.f, 0.f};
#pragma unroll
    for (int s = 0; s < 2; ++s)
#pragma unroll
      for (int t = 0; t < 4; ++t) {
        acc2[t] = __builtin_amdgcn_mfma_f32_16x16x32_bf16(hh[s], b2h[s * 4 + t], acc2[t], 0, 0, 0);
        acc2[t] = __builtin_amdgcn_mfma_f32_16x16x32_bf16(hl[s], b2h[s * 4 + t], acc2[t], 0, 0, 0);
        acc2[t] = __builtin_amdgcn_mfma_f32_16x16x32_bf16(hh[s], b2l[s * 4 + t], acc2[t], 0, 0, 0);
      }
#pragma unroll
    for (int t = 0; t < 4; ++t)
#pragma unroll
      for (int r = 0; r < 4; ++r)
        sZw[(q * 4 + r) * 161 + t * 16 + m] = acc2[t][r];

    // epilogue: node=m, jj = q+4*it (<20 always); reduce over quads via shfl
    float part = 0.f;
#pragma unroll
    for (int it = 0; it < 5; ++it) {
      int jj = q + 4 * it;
      float zi = sZw[m * 161 + jj] + sBias2[jj];
      float zc = sZw[m * 161 + 20 + jj] + sBias2[20 + jj];
      float zo = sZw[m * 161 + 40 + jj] + sBias2[40 + jj];
      float I = fsig(zi), T = ftanh(zc), O = fsig(zo);
      float h2 = O * ftanh(I * T);
      part += fmaxf(h2, 0.f) * sWl[jj];
    }
    part += __shfl_xor(part, 16);
    part += __shfl_xor(part, 32);
    if (q == 0) out[tau * 16 + m] = part + blv;
  }
}

extern "C" void kernel_launch(void* const* d_in, const int* in_sizes, int n_in,
                              void* d_out, int out_size, void* d_ws, size_t ws_size,
                              hipStream_t stream) {
  (void)in_sizes; (void)n_in; (void)out_size; (void)ws_size;
  const float* x = (const float*)d_in[0];
  // d_in[1] edge_index, d_in[2] edge_weight, d_in[5] theta1, d_in[9] theta2: dead
  const float* Wx1 = (const float*)d_in[3];
  const float* bx1 = (const float*)d_in[4];
  const float* bconv1 = (const float*)d_in[6];
  const float* Wx2 = (const float*)d_in[7];
  const float* bx2 = (const float*)d_in[8];
  const float* bconv2 = (const float*)d_in[10];
  const float* Wl = (const float*)d_in[11];
  const float* bl = (const float*)d_in[12];
  unsigned char* ws = (unsigned char*)d_ws;  // needs ~58.4 KB

  hipLaunchKernelGGL(pack_weights, dim3(32), dim3(256), 0, stream,
                     Wx1, bx1, bconv1, Wx2, bx2, bconv2, Wl, bl, ws);
  hipLaunchKernelGGL(gclstm_main, dim3(256), dim3(256), 0, stream,
                     x, ws, (float*)d_out);
}